// Round 7
// baseline (355.479 us; speedup 1.0000x reference)
//
#include <hip/hip_runtime.h>
#include <hip/hip_cooperative_groups.h>
#include <stdint.h>

namespace cg = cooperative_groups;

typedef unsigned short ushort_t;
typedef __attribute__((ext_vector_type(8))) __bf16 bf16x8;
typedef __attribute__((ext_vector_type(4))) float  f32x4;

// ---------- helpers ----------

__device__ __forceinline__ unsigned int f2bf(float f) {
    unsigned int u = __float_as_uint(f);
    return (u + 0x7FFFu + ((u >> 16) & 1u)) >> 16;  // RNE
}

// Cayley sign for e_a * e_b in Cl(4,1), SIG = [1,1,1,1,-1]
__device__ __forceinline__ float cayley_sign(int a, int b) {
    int s = 0;
    int aa = a >> 1;
    while (aa) { s += __popc(aa & b); aa >>= 1; }
    float sign = (s & 1) ? -1.0f : 1.0f;
    if (a & b & 16) sign = -sign;   // only SIG[4] = -1
    return sign;
}

// async global->LDS, 16 bytes per lane. LDS dest is wave-uniform base + lane*16.
__device__ __forceinline__ void async16(const ushort_t* g, const ushort_t* l) {
    const __attribute__((address_space(1))) unsigned int* gp =
        (const __attribute__((address_space(1))) unsigned int*)(uintptr_t)g;
    __attribute__((address_space(3))) unsigned int* lp =
        (__attribute__((address_space(3))) unsigned int*)(unsigned int)(uintptr_t)l;
    __builtin_amdgcn_global_load_lds(gp, lp, 16, 0, 0);
}

// ---------- GEMM phase macros (round-3 schedule, verbatim) ----------

#define MFMA16(a, b, c) __builtin_amdgcn_mfma_f32_16x16x32_bf16(a, b, c, 0, 0, 0)

#define RD_A4(d0, d1, d2, d3, base, KH, TMB) do {                              \
        const ushort_t* _p = (base) + aOff + (KH) * 8192 + (TMB) * 128;        \
        d0 = *(const bf16x8*)(_p + 0 * 128);                                   \
        d1 = *(const bf16x8*)(_p + 1 * 128);                                   \
        d2 = *(const bf16x8*)(_p + 2 * 128);                                   \
        d3 = *(const bf16x8*)(_p + 3 * 128);                                   \
    } while (0)

#define RD_B4(d0, d1, d2, d3, base, KH) do {                                   \
        const ushort_t* _p = (base) + bOff + (KH) * 8192;                      \
        d0 = *(const bf16x8*)(_p + 0 * 128);                                   \
        d1 = *(const bf16x8*)(_p + 1 * 128);                                   \
        d2 = *(const bf16x8*)(_p + 2 * 128);                                   \
        d3 = *(const bf16x8*)(_p + 3 * 128);                                   \
    } while (0)

#define PHASE(STAGE_STMT, RD_STMT, TMB, A0, A1, A2, A3, TAIL)                  \
    {                                                                          \
        STAGE_STMT;                                                            \
        RD_STMT;                                                               \
        __builtin_amdgcn_sched_barrier(0);                                     \
        __builtin_amdgcn_s_setprio(1);                                         \
        acc[(TMB) + 0][0] = MFMA16(A0, B0_, acc[(TMB) + 0][0]);                \
        acc[(TMB) + 0][1] = MFMA16(A0, B1_, acc[(TMB) + 0][1]);                \
        acc[(TMB) + 0][2] = MFMA16(A0, B2_, acc[(TMB) + 0][2]);                \
        acc[(TMB) + 0][3] = MFMA16(A0, B3_, acc[(TMB) + 0][3]);                \
        acc[(TMB) + 1][0] = MFMA16(A1, B0_, acc[(TMB) + 1][0]);                \
        acc[(TMB) + 1][1] = MFMA16(A1, B1_, acc[(TMB) + 1][1]);                \
        acc[(TMB) + 1][2] = MFMA16(A1, B2_, acc[(TMB) + 1][2]);                \
        acc[(TMB) + 1][3] = MFMA16(A1, B3_, acc[(TMB) + 1][3]);                \
        acc[(TMB) + 2][0] = MFMA16(A2, B0_, acc[(TMB) + 2][0]);                \
        acc[(TMB) + 2][1] = MFMA16(A2, B1_, acc[(TMB) + 2][1]);                \
        acc[(TMB) + 2][2] = MFMA16(A2, B2_, acc[(TMB) + 2][2]);                \
        acc[(TMB) + 2][3] = MFMA16(A2, B3_, acc[(TMB) + 2][3]);                \
        acc[(TMB) + 3][0] = MFMA16(A3, B0_, acc[(TMB) + 3][0]);                \
        acc[(TMB) + 3][1] = MFMA16(A3, B1_, acc[(TMB) + 3][1]);                \
        acc[(TMB) + 3][2] = MFMA16(A3, B2_, acc[(TMB) + 3][2]);                \
        acc[(TMB) + 3][3] = MFMA16(A3, B3_, acc[(TMB) + 3][3]);                \
        __builtin_amdgcn_s_setprio(0);                                         \
        TAIL;                                                                  \
        __builtin_amdgcn_s_barrier();                                          \
    }

// ---------- single cooperative kernel: prep -> grid.sync -> gemm+norm ----------

__global__ __launch_bounds__(512, 2) void fused_versor(const float* __restrict__ x,
                                                       const float* __restrict__ w,
                                                       ushort_t* __restrict__ A_sw,
                                                       ushort_t* __restrict__ B_sw,
                                                       float* __restrict__ out) {
    __shared__ ushort_t As[2][16384];   // 2 x 32 KiB
    __shared__ ushort_t Bs[2][16384];   // 2 x 32 KiB  (128 KiB total, 1 block/CU)

    // ================= PHASE 1: prep A_sw / B_sw (grid-strided) =================
    // Identical index math to the old prepAB kernel: virtual 256-thread units,
    // each real 512-thread block covers 2 whole units per iteration.
    {
        const int rtid = blockIdx.x * 512 + threadIdx.x;   // 0..131071
#pragma unroll 1
        for (int it = 0; it < 16; ++it) {                  // ---- A path ----
            const int v  = rtid + it * 131072;             // 0..2097151
            const int tu = v & 255;
            const int vb = v >> 8;                         // virtual block 0..8191
            const int k_blk = vb & 127;
            const int y  = vb >> 7;                        // 0..63
            const int p_blk = y >> 1, sub = y & 1;
            const int r  = sub * 64 + (tu >> 2);
            const int kq = tu & 3;
            const int kt = k_blk >> 1, kh = k_blk & 1;

            const int R = p_blk * 128 + r;
            const float* src = x + (size_t)R * 4096 + (size_t)k_blk * 32 + kq * 8;
            float4 a = ((const float4*)src)[0];
            float4 b = ((const float4*)src)[1];
            uint4 pk;
            pk.x = f2bf(a.x) | (f2bf(a.y) << 16);
            pk.y = f2bf(a.z) | (f2bf(a.w) << 16);
            pk.z = f2bf(b.x) | (f2bf(b.y) << 16);
            pk.w = f2bf(b.z) | (f2bf(b.w) << 16);
            const int P = R >> 8, rowp = R & 255;
            *(uint4*)(A_sw + (size_t)(P * 64 + kt) * 16384 + kh * 8192 + kq * 2048 + rowp * 8) = pk;
        }
#pragma unroll 1
        for (int it = 0; it < 16; ++it) {                  // ---- B path ----
            const int v  = rtid + it * 131072;
            const int tu = v & 255;
            const int vb = v >> 8;
            const int k_blk = vb & 127;
            const int y  = vb >> 7;
            const int p_blk = y >> 1, sub = y & 1;
            const int r  = sub * 64 + (tu >> 2);
            const int kq = tu & 3;
            const int kt = k_blk >> 1, kh = k_blk & 1;

            const int n = p_blk * 128 + r;
            const int o = n >> 5;
            const int kc = n & 31;
            const float* wrow = w + (size_t)o * 4096 + (size_t)k_blk * 32;
            unsigned int pk[4];
#pragma unroll
            for (int pr = 0; pr < 4; ++pr) {
                const int i0 = kq * 8 + pr * 2, i1 = i0 + 1;
                const int j0 = i0 ^ kc, j1 = i1 ^ kc;
                float v0 = wrow[j0] * cayley_sign(i0, j0);
                float v1 = wrow[j1] * cayley_sign(i1, j1);
                pk[pr] = f2bf(v0) | (f2bf(v1) << 16);
            }
            uint4 u = {pk[0], pk[1], pk[2], pk[3]};
            const int P = n >> 8, colp = n & 255;
            *(uint4*)(B_sw + (size_t)(P * 64 + kt) * 16384 + kh * 8192 + kq * 2048 + colp * 8) = u;
        }
    }

    // device-scope release; grid barrier; device-scope acquire (cross-XCD, G16)
    __threadfence();
    cg::this_grid().sync();
    __threadfence();

    // ================= PHASE 2: GEMM + fused norm (round-3 schedule) =================
    // XCD-aware bijective swizzle over the 256-block grid (256 % 8 == 0)
    int id = blockIdx.x;
    id = (id & 7) * 32 + (id >> 3);
    const int m_blk = id >> 4;          // 0..15
    const int n_blk = id & 15;          // 0..15

    const int t    = threadIdx.x;
    const int wave = t >> 6;            // 0..7
    const int lane = t & 63;
    const int wr = wave >> 2;           // 0..1
    const int wc = wave & 3;            // 0..3
    const int lg = lane >> 4;           // 0..3
    const int lm = lane & 15;           // 0..15

    const int aOff = (lg * 256 + wr * 128 + lm) * 8;   // elem offset into A image
    const int bOff = (lg * 256 + wc * 64  + lm) * 8;   // elem offset into B image

    const ushort_t* aPanel = A_sw + (size_t)m_blk * 64 * 16384;
    const ushort_t* bPanel = B_sw + (size_t)n_blk * 64 * 16384;

    f32x4 acc[8][4];
#pragma unroll
    for (int i = 0; i < 8; ++i)
#pragma unroll
        for (int j = 0; j < 4; ++j)
#pragma unroll
            for (int k = 0; k < 4; ++k) acc[i][j][k] = 0.0f;

    const int so = wave * 1024 + lane * 8;
    const int sl = wave * 1024;

    auto STAGE2 = [&](const ushort_t* src, ushort_t* ldsb) {
        async16(src + so,       ldsb + sl);
        async16(src + so + 512, ldsb + sl + 512);
    };

    const int NT = 64;

    // prologue: B(0)h0, A(0)h0, B(0)h1, A(0)h1, B(1)h0, A(1)h0, B(1)h1
    STAGE2(bPanel + 0,             &Bs[0][0]);
    STAGE2(aPanel + 0,             &As[0][0]);
    STAGE2(bPanel + 8192,          &Bs[0][8192]);
    STAGE2(aPanel + 8192,          &As[0][8192]);
    STAGE2(bPanel + 16384,         &Bs[1][0]);
    STAGE2(aPanel + 16384,         &As[1][0]);
    STAGE2(bPanel + 16384 + 8192,  &Bs[1][8192]);
    asm volatile("s_waitcnt vmcnt(10)" ::: "memory");   // B(0)h0, A(0)h0 landed
    __builtin_amdgcn_s_barrier();

    bf16x8 aX0, aX1, aX2, aX3, aY0, aY1, aY2, aY3;
    bf16x8 bX0, bX1, bX2, bX3, bY0, bY1, bY2, bY3;

    RD_A4(aX0, aX1, aX2, aX3, &As[0][0], 0, 0);
    RD_B4(bX0, bX1, bX2, bX3, &Bs[0][0], 0);

#define B0_ bX0
#define B1_ bX1
#define B2_ bX2
#define B3_ bX3

#pragma unroll 2
    for (int tt = 0; tt < NT - 2; ++tt) {
        const int b = tt & 1;
        const ushort_t* Ac = &As[b][0];
        const ushort_t* Bc = &Bs[b][0];
        const ushort_t* An = &As[b ^ 1][0];
        const ushort_t* Bn = &Bs[b ^ 1][0];

        // ph0: MFMA(tm0-3, kh0); read aY; stage A(t+1)h1 -> As[b^1]h1; vmcnt(8)
        PHASE(STAGE2(aPanel + (size_t)(tt + 1) * 16384 + 8192, &As[b ^ 1][8192]),
              RD_A4(aY0, aY1, aY2, aY3, Ac, 0, 4),
              0, aX0, aX1, aX2, aX3,
              asm volatile("s_waitcnt vmcnt(8)" ::: "memory"))

        // ph1: MFMA(tm4-7, kh0); read aX kh1, bY kh1; stage B(t+2)h0
        PHASE(STAGE2(bPanel + (size_t)(tt + 2) * 16384, &Bs[b][0]),
              RD_A4(aX0, aX1, aX2, aX3, Ac, 1, 0); RD_B4(bY0, bY1, bY2, bY3, Bc, 1),
              4, aY0, aY1, aY2, aY3,
              {})

#undef B0_
#undef B1_
#undef B2_
#undef B3_
#define B0_ bY0
#define B1_ bY1
#define B2_ bY2
#define B3_ bY3

        // ph2: MFMA(tm0-3, kh1); read aY kh1; stage A(t+2)h0; vmcnt(8)
        PHASE(STAGE2(aPanel + (size_t)(tt + 2) * 16384, &As[b][0]),
              RD_A4(aY0, aY1, aY2, aY3, Ac, 1, 4),
              0, aX0, aX1, aX2, aX3,
              asm volatile("s_waitcnt vmcnt(8)" ::: "memory"))

        // ph3: MFMA(tm4-7, kh1); read aX/bX of tile t+1; stage B(t+2)h1
        PHASE(STAGE2(bPanel + (size_t)(tt + 2) * 16384 + 8192, &Bs[b][8192]),
              RD_A4(aX0, aX1, aX2, aX3, An, 0, 0); RD_B4(bX0, bX1, bX2, bX3, Bn, 0),
              4, aY0, aY1, aY2, aY3,
              {})

#undef B0_
#undef B1_
#undef B2_
#undef B3_
#define B0_ bX0
#define B1_ bX1
#define B2_ bX2
#define B3_ bX3
    }

    // ---- peeled iter NT-2 (b = 0): stage only A(NT-1)h1 ----
    {
        const ushort_t* Ac = &As[0][0];
        const ushort_t* Bc = &Bs[0][0];
        const ushort_t* An = &As[1][0];
        const ushort_t* Bn = &Bs[1][0];

        PHASE(STAGE2(aPanel + (size_t)(NT - 1) * 16384 + 8192, &As[1][8192]),
              RD_A4(aY0, aY1, aY2, aY3, Ac, 0, 4),
              0, aX0, aX1, aX2, aX3,
              asm volatile("s_waitcnt vmcnt(8)" ::: "memory"))
        PHASE({},
              RD_A4(aX0, aX1, aX2, aX3, Ac, 1, 0); RD_B4(bY0, bY1, bY2, bY3, Bc, 1),
              4, aY0, aY1, aY2, aY3,
              {})
#undef B0_
#undef B1_
#undef B2_
#undef B3_
#define B0_ bY0
#define B1_ bY1
#define B2_ bY2
#define B3_ bY3
        PHASE({},
              RD_A4(aY0, aY1, aY2, aY3, Ac, 1, 4),
              0, aX0, aX1, aX2, aX3,
              asm volatile("s_waitcnt vmcnt(4)" ::: "memory"))
        PHASE({},
              RD_A4(aX0, aX1, aX2, aX3, An, 0, 0); RD_B4(bX0, bX1, bX2, bX3, Bn, 0),
              4, aY0, aY1, aY2, aY3,
              {})
#undef B0_
#undef B1_
#undef B2_
#undef B3_
#define B0_ bX0
#define B1_ bX1
#define B2_ bX2
#define B3_ bX3
    }
    // ---- peeled iter NT-1 (b = 1): no stages; drain to 0 at end of ph0 ----
    {
        const ushort_t* Ac = &As[1][0];
        const ushort_t* Bc = &Bs[1][0];

        PHASE({},
              RD_A4(aY0, aY1, aY2, aY3, Ac, 0, 4),
              0, aX0, aX1, aX2, aX3,
              asm volatile("s_waitcnt vmcnt(0)" ::: "memory"))
        PHASE({},
              RD_A4(aX0, aX1, aX2, aX3, Ac, 1, 0); RD_B4(bY0, bY1, bY2, bY3, Bc, 1),
              4, aY0, aY1, aY2, aY3,
              {})
#undef B0_
#undef B1_
#undef B2_
#undef B3_
#define B0_ bY0
#define B1_ bY1
#define B2_ bY2
#define B3_ bY3
        PHASE({},
              RD_A4(aY0, aY1, aY2, aY3, Ac, 1, 4),
              0, aX0, aX1, aX2, aX3,
              {})
        // final phase: MFMA only
        {
            __builtin_amdgcn_s_setprio(1);
            acc[4][0] = MFMA16(aY0, B0_, acc[4][0]);
            acc[4][1] = MFMA16(aY0, B1_, acc[4][1]);
            acc[4][2] = MFMA16(aY0, B2_, acc[4][2]);
            acc[4][3] = MFMA16(aY0, B3_, acc[4][3]);
            acc[5][0] = MFMA16(aY1, B0_, acc[5][0]);
            acc[5][1] = MFMA16(aY1, B1_, acc[5][1]);
            acc[5][2] = MFMA16(aY1, B2_, acc[5][2]);
            acc[5][3] = MFMA16(aY1, B3_, acc[5][3]);
            acc[6][0] = MFMA16(aY2, B0_, acc[6][0]);
            acc[6][1] = MFMA16(aY2, B1_, acc[6][1]);
            acc[6][2] = MFMA16(aY2, B2_, acc[6][2]);
            acc[6][3] = MFMA16(aY2, B3_, acc[6][3]);
            acc[7][0] = MFMA16(aY3, B0_, acc[7][0]);
            acc[7][1] = MFMA16(aY3, B1_, acc[7][1]);
            acc[7][2] = MFMA16(aY3, B2_, acc[7][2]);
            acc[7][3] = MFMA16(aY3, B3_, acc[7][3]);
            __builtin_amdgcn_s_setprio(0);
        }
    }

    // ---------- fused multivector normalization + store ----------
    // C/D 16x16 layout: col = lane&15, row = (lane>>4)*4 + reg.
    const int row0 = m_blk * 256 + wr * 128;
    const int col0 = n_blk * 256 + wc * 64;
#pragma unroll
    for (int tm = 0; tm < 8; ++tm) {
#pragma unroll
        for (int u = 0; u < 2; ++u) {
#pragma unroll
            for (int reg = 0; reg < 4; ++reg) {
                float v0 = acc[tm][2 * u][reg];
                float v1 = acc[tm][2 * u + 1][reg];
                float p = v0 * v0 + v1 * v1;
                p += __shfl_xor(p, 1);
                p += __shfl_xor(p, 2);
                p += __shfl_xor(p, 4);
                p += __shfl_xor(p, 8);      // stays within the 16-lane group
                const float inv = rsqrtf(p + 1e-6f);
                const int row = row0 + tm * 16 + lg * 4 + reg;
                float* orow = out + (size_t)row * 4096 + col0 + u * 32 + lm;
                orow[0]  = v0 * inv;
                orow[16] = v1 * inv;
            }
        }
    }
}

// ---------- launch ----------

extern "C" void kernel_launch(void* const* d_in, const int* in_sizes, int n_in,
                              void* d_out, int out_size, void* d_ws, size_t ws_size,
                              hipStream_t stream) {
    const float* x = (const float*)d_in[0];     // 4096 x 128 x 32 f32
    const float* w = (const float*)d_in[1];     // 128 x 128 x 32 f32
    float* out = (float*)d_out;                 // 4096 x 128 x 32 f32

    ushort_t* A_sw = (ushort_t*)d_ws;                       // 32 MiB
    ushort_t* B_sw = A_sw + (size_t)4096 * 4096;            // 32 MiB

    void* args[5];
    args[0] = (void*)&x;
    args[1] = (void*)&w;
    args[2] = (void*)&A_sw;
    args[3] = (void*)&B_sw;
    args[4] = (void*)&out;
    hipLaunchCooperativeKernel((const void*)fused_versor, dim3(256), dim3(512),
                               args, 0, stream);
}

// Round 8
// 227.142 us; speedup vs baseline: 1.5650x; 1.5650x over previous
//
#include <hip/hip_runtime.h>
#include <stdint.h>

typedef unsigned short ushort_t;
typedef __attribute__((ext_vector_type(8))) __bf16 bf16x8;
typedef __attribute__((ext_vector_type(4))) float  f32x4;

// ---------- helpers ----------

__device__ __forceinline__ unsigned int f2bf(float f) {
    unsigned int u = __float_as_uint(f);
    return (u + 0x7FFFu + ((u >> 16) & 1u)) >> 16;  // RNE
}

// Cayley sign for e_a * e_b in Cl(4,1), SIG = [1,1,1,1,-1]
__device__ __forceinline__ float cayley_sign(int a, int b) {
    int s = 0;
    int aa = a >> 1;
    while (aa) { s += __popc(aa & b); aa >>= 1; }
    float sign = (s & 1) ? -1.0f : 1.0f;
    if (a & b & 16) sign = -sign;   // only SIG[4] = -1
    return sign;
}

// async global->LDS, 16 bytes per lane. LDS dest is wave-uniform base + lane*16.
__device__ __forceinline__ void async16(const ushort_t* g, const ushort_t* l) {
    const __attribute__((address_space(1))) unsigned int* gp =
        (const __attribute__((address_space(1))) unsigned int*)(uintptr_t)g;
    __attribute__((address_space(3))) unsigned int* lp =
        (__attribute__((address_space(3))) unsigned int*)(unsigned int)(uintptr_t)l;
    __builtin_amdgcn_global_load_lds(gp, lp, 16, 0, 0);
}

// ---------- merged prep kernel (round-3 version, verbatim) ----------
// Operand image per (panel P of 256 rows, k-tile kt of 64): 16384 bf16 laid out
// [k8(8)][row(256)][j(8)], k = k8*8+j. Each 16 KiB half = one staging half-tile.
__global__ __launch_bounds__(256) void prepAB(const float* __restrict__ x,
                                              const float* __restrict__ w,
                                              ushort_t* __restrict__ A_sw,
                                              ushort_t* __restrict__ B_sw) {
    const int k_blk = blockIdx.x;            // 0..127 (32-k chunk)
    const int p_blk = blockIdx.y >> 1;       // 0..31 (128-row panel)
    const int sub   = blockIdx.y & 1;        // 0..1  (64-row half)
    const int t = threadIdx.x;               // 0..255
    const int r  = sub * 64 + (t >> 2);      // 0..127 row/col within 128-panel
    const int kq = t & 3;                    // 0..3

    const int kt = k_blk >> 1;               // 64-k tile index (0..63)
    const int kh = k_blk & 1;                // which 32-k half of the tile

    if (blockIdx.z == 0) {
        // ---- A: x viewed as 4096 x 4096 row-major f32 -> bf16 swizzled ----
        const int R = p_blk * 128 + r;
        const float* src = x + (size_t)R * 4096 + (size_t)k_blk * 32 + kq * 8;
        float4 a = ((const float4*)src)[0];
        float4 b = ((const float4*)src)[1];
        uint4 pk;
        pk.x = f2bf(a.x) | (f2bf(a.y) << 16);
        pk.y = f2bf(a.z) | (f2bf(a.w) << 16);
        pk.z = f2bf(b.x) | (f2bf(b.y) << 16);
        pk.w = f2bf(b.z) | (f2bf(b.w) << 16);
        const int P = R >> 8, rowp = R & 255;
        *(uint4*)(A_sw + (size_t)(P * 64 + kt) * 16384 + kh * 8192 + kq * 2048 + rowp * 8) = pk;
    } else {
        // ---- B: Bt[n][f*32+i] = W[o, f, i^kc] * sgn(i, i^kc), n = o*32+kc ----
        const int n = p_blk * 128 + r;
        const int o = n >> 5;
        const int kc = n & 31;
        const float* wrow = w + (size_t)o * 4096 + (size_t)k_blk * 32;
        unsigned int pk[4];
#pragma unroll
        for (int pr = 0; pr < 4; ++pr) {
            const int i0 = kq * 8 + pr * 2, i1 = i0 + 1;
            const int j0 = i0 ^ kc, j1 = i1 ^ kc;
            float v0 = wrow[j0] * cayley_sign(i0, j0);
            float v1 = wrow[j1] * cayley_sign(i1, j1);
            pk[pr] = f2bf(v0) | (f2bf(v1) << 16);
        }
        uint4 u = {pk[0], pk[1], pk[2], pk[3]};
        const int P = n >> 8, colp = n & 255;
        *(uint4*)(B_sw + (size_t)(P * 64 + kt) * 16384 + kh * 8192 + kq * 2048 + colp * 8) = u;
    }
}

// ---------- GEMM: 256x256, BK=64, 8 waves, m201-style 2-barrier phases ----------
// Phase p: { ds_read THIS phase's frags; stage 1 half-tile; BARRIER;
//            lgkmcnt(0); setprio(1); 16 pure MFMA; setprio(0); [vmcnt(10)]; BARRIER }
// Pure MFMA cluster between barriers -> 2 waves/SIMD issue MFMA back-to-back with
// no DS/VMEM interleave; the barrier wait absorbs ds_read latency.
// Stage slots (same as round 3, hazards re-verified for 2-barrier structure):
//   ph0: A(t+1)h1 -> As[b^1]h1   (Ah1(b^1) last read t-1 ph3-top, >=1 barrier ago)
//   ph1: B(t+2)h0 -> Bs[b]h0     (Bh0(b) last read t ph0-top)
//   ph2: A(t+2)h0 -> As[b]h0     (Ah0(b) last read t ph1-top)
//   ph3: B(t+2)h1 -> Bs[b]h1     (Bh1(b) last read t ph2-top)
// vmcnt(10) at ph1-end (drains A(t)h1,B(t)h1 for ph2 reads) and ph3-end
// (drains A(t+1)h0,B(t+1)h0 for next-tile ph0 reads). In-flight: 14 max -> 10.

#define MFMA16(a, b, c) __builtin_amdgcn_mfma_f32_16x16x32_bf16(a, b, c, 0, 0, 0)

#define RD_A4(base, KH, TMB) do {                                              \
        const ushort_t* _p = (base) + aOff + (KH) * 8192 + (TMB) * 128;        \
        fa0 = *(const bf16x8*)(_p + 0 * 128);                                  \
        fa1 = *(const bf16x8*)(_p + 1 * 128);                                  \
        fa2 = *(const bf16x8*)(_p + 2 * 128);                                  \
        fa3 = *(const bf16x8*)(_p + 3 * 128);                                  \
    } while (0)

#define RD_B4(base, KH) do {                                                   \
        const ushort_t* _p = (base) + bOff + (KH) * 8192;                      \
        fb0 = *(const bf16x8*)(_p + 0 * 128);                                  \
        fb1 = *(const bf16x8*)(_p + 1 * 128);                                  \
        fb2 = *(const bf16x8*)(_p + 2 * 128);                                  \
        fb3 = *(const bf16x8*)(_p + 3 * 128);                                  \
    } while (0)

#define PH(RD_STMT, STAGE_STMT, TMB, TAILVM)                                   \
    {                                                                          \
        RD_STMT;                                                               \
        STAGE_STMT;                                                            \
        __builtin_amdgcn_sched_barrier(0);                                     \
        __builtin_amdgcn_s_barrier();                                          \
        asm volatile("s_waitcnt lgkmcnt(0)" ::: "memory");                     \
        __builtin_amdgcn_sched_barrier(0);                                     \
        __builtin_amdgcn_s_setprio(1);                                         \
        acc[(TMB) + 0][0] = MFMA16(fa0, fb0, acc[(TMB) + 0][0]);               \
        acc[(TMB) + 0][1] = MFMA16(fa0, fb1, acc[(TMB) + 0][1]);               \
        acc[(TMB) + 0][2] = MFMA16(fa0, fb2, acc[(TMB) + 0][2]);               \
        acc[(TMB) + 0][3] = MFMA16(fa0, fb3, acc[(TMB) + 0][3]);               \
        acc[(TMB) + 1][0] = MFMA16(fa1, fb0, acc[(TMB) + 1][0]);               \
        acc[(TMB) + 1][1] = MFMA16(fa1, fb1, acc[(TMB) + 1][1]);               \
        acc[(TMB) + 1][2] = MFMA16(fa1, fb2, acc[(TMB) + 1][2]);               \
        acc[(TMB) + 1][3] = MFMA16(fa1, fb3, acc[(TMB) + 1][3]);               \
        acc[(TMB) + 2][0] = MFMA16(fa2, fb0, acc[(TMB) + 2][0]);               \
        acc[(TMB) + 2][1] = MFMA16(fa2, fb1, acc[(TMB) + 2][1]);               \
        acc[(TMB) + 2][2] = MFMA16(fa2, fb2, acc[(TMB) + 2][2]);               \
        acc[(TMB) + 2][3] = MFMA16(fa2, fb3, acc[(TMB) + 2][3]);               \
        acc[(TMB) + 3][0] = MFMA16(fa3, fb0, acc[(TMB) + 3][0]);               \
        acc[(TMB) + 3][1] = MFMA16(fa3, fb1, acc[(TMB) + 3][1]);               \
        acc[(TMB) + 3][2] = MFMA16(fa3, fb2, acc[(TMB) + 3][2]);               \
        acc[(TMB) + 3][3] = MFMA16(fa3, fb3, acc[(TMB) + 3][3]);               \
        __builtin_amdgcn_s_setprio(0);                                         \
        TAILVM;                                                                \
        __builtin_amdgcn_s_barrier();                                          \
    }

__global__ __launch_bounds__(512, 2) void gemm_norm(const ushort_t* __restrict__ A_sw,
                                                    const ushort_t* __restrict__ B_sw,
                                                    float* __restrict__ out) {
    __shared__ ushort_t As[2][16384];   // 2 x 32 KiB
    __shared__ ushort_t Bs[2][16384];   // 2 x 32 KiB  (128 KiB total, 1 block/CU)

    // XCD-aware bijective swizzle over the 256-block grid (256 % 8 == 0)
    int id = blockIdx.x;
    id = (id & 7) * 32 + (id >> 3);
    const int m_blk = id >> 4;          // 0..15
    const int n_blk = id & 15;          // 0..15

    const int t    = threadIdx.x;
    const int wave = t >> 6;            // 0..7
    const int lane = t & 63;
    const int wr = wave >> 2;           // 0..1
    const int wc = wave & 3;            // 0..3
    const int lg = lane >> 4;           // 0..3
    const int lm = lane & 15;           // 0..15

    const int aOff = (lg * 256 + wr * 128 + lm) * 8;   // elem offset into A image
    const int bOff = (lg * 256 + wc * 64  + lm) * 8;   // elem offset into B image

    const ushort_t* aPanel = A_sw + (size_t)m_blk * 64 * 16384;
    const ushort_t* bPanel = B_sw + (size_t)n_blk * 64 * 16384;

    f32x4 acc[8][4];
#pragma unroll
    for (int i = 0; i < 8; ++i)
#pragma unroll
        for (int j = 0; j < 4; ++j)
#pragma unroll
            for (int k = 0; k < 4; ++k) acc[i][j][k] = 0.0f;

    const int so = wave * 1024 + lane * 8;
    const int sl = wave * 1024;

    auto STAGE2 = [&](const ushort_t* src, ushort_t* ldsb) {
        async16(src + so,       ldsb + sl);
        async16(src + so + 512, ldsb + sl + 512);
    };

    const int NT = 64;

    // prologue (14 loads): A0h0, B0h0, A0h1, B0h1, A1h0, B1h0, B1h1
    STAGE2(aPanel + 0,             &As[0][0]);
    STAGE2(bPanel + 0,             &Bs[0][0]);
    STAGE2(aPanel + 8192,          &As[0][8192]);
    STAGE2(bPanel + 8192,          &Bs[0][8192]);
    STAGE2(aPanel + 16384,         &As[1][0]);
    STAGE2(bPanel + 16384,         &Bs[1][0]);
    STAGE2(bPanel + 16384 + 8192,  &Bs[1][8192]);
    asm volatile("s_waitcnt vmcnt(10)" ::: "memory");   // A0h0, B0h0 landed
    __builtin_amdgcn_s_barrier();

    bf16x8 fa0, fa1, fa2, fa3, fb0, fb1, fb2, fb3;

#pragma unroll 2
    for (int tt = 0; tt < NT - 2; ++tt) {
        const int b = tt & 1;
        const ushort_t* Ac = &As[b][0];
        const ushort_t* Bc = &Bs[b][0];

        // ph0: rd A(kh0,tm0-3)+B(kh0); stage A(t+1)h1 -> As[b^1]h1
        PH({ RD_A4(Ac, 0, 0); RD_B4(Bc, 0); },
           STAGE2(aPanel + (size_t)(tt + 1) * 16384 + 8192, &As[b ^ 1][8192]),
           0, {})
        // ph1: rd A(kh0,tm4-7) [B reused]; stage B(t+2)h0; vmcnt(10)
        PH(RD_A4(Ac, 0, 4),
           STAGE2(bPanel + (size_t)(tt + 2) * 16384, &Bs[b][0]),
           4, asm volatile("s_waitcnt vmcnt(10)" ::: "memory"))
        // ph2: rd A(kh1,tm0-3)+B(kh1); stage A(t+2)h0
        PH({ RD_A4(Ac, 1, 0); RD_B4(Bc, 1); },
           STAGE2(aPanel + (size_t)(tt + 2) * 16384, &As[b][0]),
           0, {})
        // ph3: rd A(kh1,tm4-7); stage B(t+2)h1; vmcnt(10)
        PH(RD_A4(Ac, 1, 4),
           STAGE2(bPanel + (size_t)(tt + 2) * 16384 + 8192, &Bs[b][8192]),
           4, asm volatile("s_waitcnt vmcnt(10)" ::: "memory"))
    }

    // ---- peeled tile NT-2 (b=0): stage only A(63)h1; waits 8 then 4 ----
    {
        const ushort_t* Ac = &As[0][0];
        const ushort_t* Bc = &Bs[0][0];

        PH({ RD_A4(Ac, 0, 0); RD_B4(Bc, 0); },
           STAGE2(aPanel + (size_t)(NT - 1) * 16384 + 8192, &As[1][8192]),
           0, {})
        PH(RD_A4(Ac, 0, 4), {},
           4, asm volatile("s_waitcnt vmcnt(8)" ::: "memory"))
        PH({ RD_A4(Ac, 1, 0); RD_B4(Bc, 1); }, {},
           0, {})
        PH(RD_A4(Ac, 1, 4), {},
           4, asm volatile("s_waitcnt vmcnt(4)" ::: "memory"))
    }
    // ---- peeled tile NT-1 (b=1): no stages; drain at ph1 ----
    {
        const ushort_t* Ac = &As[1][0];
        const ushort_t* Bc = &Bs[1][0];

        PH({ RD_A4(Ac, 0, 0); RD_B4(Bc, 0); }, {},
           0, {})
        PH(RD_A4(Ac, 0, 4), {},
           4, asm volatile("s_waitcnt vmcnt(0)" ::: "memory"))
        PH({ RD_A4(Ac, 1, 0); RD_B4(Bc, 1); }, {},
           0, {})
        PH(RD_A4(Ac, 1, 4), {},
           4, {})
    }

    // ---------- fused multivector normalization + store ----------
    // C/D 16x16 layout: col = lane&15, row = (lane>>4)*4 + reg.
    const int row0 = m_blk * 256 + wr * 128;
    const int col0 = n_blk * 256 + wc * 64;
#pragma unroll
    for (int tm = 0; tm < 8; ++tm) {
#pragma unroll
        for (int u = 0; u < 2; ++u) {
#pragma unroll
            for (int reg = 0; reg < 4; ++reg) {
                float v0 = acc[tm][2 * u][reg];
                float v1 = acc[tm][2 * u + 1][reg];
                float p = v0 * v0 + v1 * v1;
                p += __shfl_xor(p, 1);
                p += __shfl_xor(p, 2);
                p += __shfl_xor(p, 4);
                p += __shfl_xor(p, 8);      // stays within the 16-lane group
                const float inv = rsqrtf(p + 1e-6f);
                const int row = row0 + tm * 16 + lg * 4 + reg;
                float* orow = out + (size_t)row * 4096 + col0 + u * 32 + lm;
                orow[0]  = v0 * inv;
                orow[16] = v1 * inv;
            }
        }
    }
}

// ---------- launch ----------

extern "C" void kernel_launch(void* const* d_in, const int* in_sizes, int n_in,
                              void* d_out, int out_size, void* d_ws, size_t ws_size,
                              hipStream_t stream) {
    const float* x = (const float*)d_in[0];     // 4096 x 128 x 32 f32
    const float* w = (const float*)d_in[1];     // 128 x 128 x 32 f32
    float* out = (float*)d_out;                 // 4096 x 128 x 32 f32

    ushort_t* A_sw = (ushort_t*)d_ws;                       // 32 MiB
    ushort_t* B_sw = A_sw + (size_t)4096 * 4096;            // 32 MiB

    prepAB<<<dim3(128, 64, 2), 256, 0, stream>>>(x, w, A_sw, B_sw);
    gemm_norm<<<dim3(256), 512, 0, stream>>>(A_sw, B_sw, out);
}